// Round 1
// baseline (240.364 us; speedup 1.0000x reference)
//
#include <hip/hip_runtime.h>
#include <math.h>

#define N_TOT   196608      // B*HW*SPP = 4*16384*3
#define HWSPP   49152       // 16384*3
#define RGF     82          // floats per raw gaussian
#define RGS     83          // padded LDS stride

#define OFF_MEANS 0
#define OFF_COV   589824
#define OFF_SH    2359296
#define OFF_OP    17104896
#define OFF_FEAT  17301504
#define OFF_SCL   29884416
#define OFF_ROT   30474240

// workspace float layout: [0,660) D matrices (b*165 + loff[l]); [660,696) Kinv b*9; [696,700) multiplier
__device__ __constant__ int c_loff[5] = {0, 1, 10, 35, 84};

__device__ __forceinline__ float sigmoidf_(float x) { return 1.0f / (1.0f + expf(-x)); }

// ---------------- setup: angles + Wigner D (fp64, expm by scaling&squaring) ----------------
__global__ __launch_bounds__(256) void setup_kernel(
    const float* __restrict__ extr, const float* __restrict__ intr,
    const int* __restrict__ img_h, const int* __restrict__ img_w,
    float* __restrict__ ws)
{
  const int b = blockIdx.x / 5;
  const int l = blockIdx.x % 5;
  const int n = 2 * l + 1;
  const int nn = n * n;
  const int t = threadIdx.x;

  __shared__ double Qr[81], Qi[81], X0c[81], Trr[81], Tii[81], X0r[81], X1r[81];
  __shared__ double GA[3][81], GP[3][81], GT[3][81], OUT3[3][81], M1[81];
  __shared__ double ang[3];
  __shared__ int s3[3];
  __shared__ int smax;

  if (t == 0) {
    const float* E = extr + b * 16;
    double R00 = E[0], R01 = E[1], R02 = E[2];
    double R11 = E[5];
    double R20 = E[8], R21 = E[9], R22 = E[10];
    double x0 = R01, x1 = R11, x2 = R21;
    double nr = sqrt(x0 * x0 + x1 * x1 + x2 * x2);
    x0 /= nr; x1 /= nr; x2 /= nr;
    double beta  = acos(fmin(1.0, fmax(-1.0, x1)));
    double alpha = atan2(x0, x2);
    double ca = cos(alpha), sa = sin(alpha);
    double gamma = atan2(ca * R02 - sa * R22, ca * R00 - sa * R20);
    ang[0] = alpha; ang[1] = beta; ang[2] = gamma;
    if (l == 0) {
      const float* K = intr + b * 9;
      double k00=K[0],k01=K[1],k02=K[2],k10=K[3],k11=K[4],k12=K[5],k20=K[6],k21=K[7],k22=K[8];
      double det = k00*(k11*k22-k12*k21) - k01*(k10*k22-k12*k20) + k02*(k10*k21-k11*k20);
      double id = 1.0 / det;
      float* kv = ws + 660 + b * 9;
      kv[0] = (float)((k11*k22-k12*k21)*id);
      kv[1] = (float)((k02*k21-k01*k22)*id);
      kv[2] = (float)((k01*k12-k02*k11)*id);
      kv[3] = (float)((k12*k20-k10*k22)*id);
      kv[4] = (float)((k00*k22-k02*k20)*id);
      kv[5] = (float)((k02*k10-k00*k12)*id);
      kv[6] = (float)((k10*k21-k11*k20)*id);
      kv[7] = (float)((k01*k20-k00*k21)*id);
      kv[8] = (float)((k00*k11-k01*k10)*id);
      double d2 = k00 * k11 - k01 * k10;
      double ps0 = 1.0 / (double)img_w[0];
      double ps1 = 1.0 / (double)img_h[0];
      double sum = (k11 * ps0 - k01 * ps1 - k10 * ps0 + k00 * ps1) / d2;
      ws[696 + b] = (float)(0.1 * sum);
    }
  }
  if (t < 81) { Qr[t] = 0.0; Qi[t] = 0.0; X0c[t] = 0.0; }
  __syncthreads();
  if (t == 0) {
    const double irt2 = 0.70710678118654752440;
    for (int m = -l; m < 0; ++m) {
      Qr[(l + m) * n + (l - m)] = irt2;      // q[l+m, l+|m|] = 1/sqrt2
      Qi[(l + m) * n + (l + m)] = -irt2;     // q[l+m, l-|m|] = -i/sqrt2
    }
    Qr[l * n + l] = 1.0;
    for (int m = 1; m <= l; ++m) {
      double sg = (m & 1) ? -1.0 : 1.0;
      Qr[(l + m) * n + (l + m)] = sg * irt2; // (-1)^m/sqrt2
      Qi[(l + m) * n + (l - m)] = sg * irt2; // i(-1)^m/sqrt2
    }
    // X0 = 0.5*(raising+lowering): upper +0.5c, lower -0.5c
    for (int i = 0; i < n - 1; ++i) {
      double mi = (double)(-l + i);
      double ci = sqrt((double)(l * (l + 1)) - mi * (mi + 1.0));
      X0c[i * n + (i + 1)] = 0.5 * ci;
      X0c[(i + 1) * n + i] = -0.5 * ci;
    }
  }
  __syncthreads();
  if (t < nn) {  // T = X0c @ Q (X0c real)
    int i = t / n, j = t % n; double s = 0, s2 = 0;
    for (int k = 0; k < n; ++k) { s += X0c[i*n+k]*Qr[k*n+j]; s2 += X0c[i*n+k]*Qi[k*n+j]; }
    Trr[t] = s; Tii[t] = s2;
  }
  __syncthreads();
  if (t < nn) {  // X0r = Re(Q^H T);  X1r = Re(Q^H diag(i m) Q)
    int a = t / n, c = t % n; double s = 0, s1 = 0;
    for (int r = 0; r < n; ++r) {
      s  += Qr[r*n+a]*Trr[r*n+c] + Qi[r*n+a]*Tii[r*n+c];
      double mr = (double)(r - l);
      s1 += mr * (Qi[r*n+a]*Qr[r*n+c] - Qr[r*n+a]*Qi[r*n+c]);
    }
    X0r[t] = s; X1r[t] = s1;
  }
  __syncthreads();

  // three expm's concurrently: g=0: exp(alpha X1), g=1: exp(-beta X0), g=2: exp(gamma X1)
  const int g  = t / 81;   // valid when t < 243
  const int gt = t - g * 81;
  if (t < 243 && gt == 0) {
    const double* X = (g == 1) ? X0r : X1r;
    double th = (g == 0) ? ang[0] : ((g == 1) ? -ang[1] : ang[2]);
    double mx = 0.0;
    for (int i = 0; i < n; ++i) {
      double rs = 0.0;
      for (int j = 0; j < n; ++j) rs += fabs(th * X[i * n + j]);
      mx = fmax(mx, rs);
    }
    int s = 0;
    while (mx > 0.25) { mx *= 0.5; ++s; }
    s3[g] = s;
  }
  __syncthreads();
  if (t == 0) smax = max(s3[0], max(s3[1], s3[2]));
  __syncthreads();
  if (t < 243 && gt < nn) {
    const double* X = (g == 1) ? X0r : X1r;
    double th = (g == 0) ? ang[0] : ((g == 1) ? -ang[1] : ang[2]);
    for (int q = 0; q < s3[g]; ++q) th *= 0.5;
    GA[g][gt] = th * X[gt];
    GP[g][gt] = GA[g][gt];
    OUT3[g][gt] = ((gt / n) == (gt % n) ? 1.0 : 0.0) + GA[g][gt];
  }
  __syncthreads();
  for (int k = 2; k <= 14; ++k) {  // Taylor
    if (t < 243 && gt < nn) {
      int i = gt / n, j = gt % n; double s = 0;
      for (int kk = 0; kk < n; ++kk) s += GP[g][i*n+kk] * GA[g][kk*n+j];
      GT[g][gt] = s;
    }
    __syncthreads();
    if (t < 243 && gt < nn) { GP[g][gt] = GT[g][gt] / (double)k; OUT3[g][gt] += GP[g][gt]; }
    __syncthreads();
  }
  for (int q = 0; q < smax; ++q) {  // squaring (idempotent copy when group done)
    if (t < 243 && gt < nn) {
      if (q < s3[g]) {
        int i = gt / n, j = gt % n; double s = 0;
        for (int kk = 0; kk < n; ++kk) s += OUT3[g][i*n+kk] * OUT3[g][kk*n+j];
        GT[g][gt] = s;
      } else GT[g][gt] = OUT3[g][gt];
    }
    __syncthreads();
    if (t < 243 && gt < nn) OUT3[g][gt] = GT[g][gt];
    __syncthreads();
  }
  // D = Ea @ Eb @ Eg
  if (t < nn) {
    int i = t / n, j = t % n; double s = 0;
    for (int k = 0; k < n; ++k) s += OUT3[0][i*n+k] * OUT3[1][k*n+j];
    M1[t] = s;
  }
  __syncthreads();
  if (t < nn) {
    int i = t / n, j = t % n; double s = 0;
    for (int k = 0; k < n; ++k) s += M1[i*n+k] * OUT3[2][k*n+j];
    ws[b * 165 + c_loff[l] + t] = (float)s;
  }
}

// ---------------- main per-gaussian kernel ----------------
__global__ __launch_bounds__(256) void gauss_kernel(
    const float* __restrict__ extr,
    const float* __restrict__ coords,
    const float* __restrict__ depths,
    const float* __restrict__ opac,
    const float* __restrict__ rg,
    const float* __restrict__ ws,
    float* __restrict__ out)
{
  __shared__ float sIn[64 * RGS];
  __shared__ __align__(16) float sSh[64 * 75];
  __shared__ float sSmall[1280];  // means[0,192) cov[192,768) scales[768,960) rot[960,1216) opac[1216,1280)
  __shared__ float sD[165];
  __shared__ float sKinv[9], sRc[9], sOrig[3];
  __shared__ float sMult;

  const int t  = threadIdx.x;
  const int g0 = blockIdx.x * 64;
  const int b  = g0 / HWSPP;

  if (t < 165) sD[t] = ws[b * 165 + t];
  else if (t < 174) sKinv[t - 165] = ws[660 + b * 9 + (t - 165)];
  else if (t < 183) { int k = t - 174; sRc[k] = extr[b * 16 + (k / 3) * 4 + (k % 3)]; }
  else if (t < 186) sOrig[t - 183] = extr[b * 16 + (t - 183) * 4 + 3];
  else if (t == 186) sMult = ws[696 + b];

  {
    const float4* src4 = (const float4*)(rg + (size_t)g0 * RGF);
    for (int idx = t; idx < (64 * RGF) / 4; idx += 256) {
      float4 v = src4[idx];
      int base = idx * 4;
      int gg = base / RGF;
      int ff = base - gg * RGF;
      float vv[4] = {v.x, v.y, v.z, v.w};
#pragma unroll
      for (int e = 0; e < 4; ++e) {
        int g2 = gg, f2 = ff + e;
        if (f2 >= RGF) { g2 += 1; f2 -= RGF; }
        sIn[g2 * RGS + f2] = vv[e];
      }
    }
  }
  __syncthreads();

  if (t < 64) {
    const int gidx = g0 + t;
    const float* q = &sIn[t * RGS];
    const float dpt = depths[gidx];
    const float mlt = sMult;
    float sc0 = (0.5f + 14.5f * sigmoidf_(q[0])) * dpt * mlt;
    float sc1 = (0.5f + 14.5f * sigmoidf_(q[1])) * dpt * mlt;
    float sc2 = (0.5f + 14.5f * sigmoidf_(q[2])) * dpt * mlt;
    float r0 = q[3], r1 = q[4], r2 = q[5], r3 = q[6];
    float nr = sqrtf(r0*r0 + r1*r1 + r2*r2 + r3*r3) + 1e-8f;
    float qr = r0/nr, qi = r1/nr, qj = r2/nr, qk = r3/nr;
    float s2 = 2.0f / (qr*qr + qi*qi + qj*qj + qk*qk);
    float R00 = 1.0f - s2*(qj*qj + qk*qk);
    float R01 = s2*(qi*qj - qk*qr);
    float R02 = s2*(qi*qk + qj*qr);
    float R10 = s2*(qi*qj + qk*qr);
    float R11 = 1.0f - s2*(qi*qi + qk*qk);
    float R12 = s2*(qj*qk - qi*qr);
    float R20 = s2*(qi*qk - qj*qr);
    float R21 = s2*(qj*qk + qi*qr);
    float R22 = 1.0f - s2*(qi*qi + qj*qj);
    float v0 = sc0*sc0, v1 = sc1*sc1, v2 = sc2*sc2;
    float C00 = R00*R00*v0 + R01*R01*v1 + R02*R02*v2;
    float C01 = R00*R10*v0 + R01*R11*v1 + R02*R12*v2;
    float C02 = R00*R20*v0 + R01*R21*v1 + R02*R22*v2;
    float C11 = R10*R10*v0 + R11*R11*v1 + R12*R12*v2;
    float C12 = R10*R20*v0 + R11*R21*v1 + R12*R22*v2;
    float C22 = R20*R20*v0 + R21*R21*v1 + R22*R22*v2;
    float2 cxy = ((const float2*)coords)[gidx];
    float dx = sKinv[0]*cxy.x + sKinv[1]*cxy.y + sKinv[2];
    float dy = sKinv[3]*cxy.x + sKinv[4]*cxy.y + sKinv[5];
    float dz = sKinv[6]*cxy.x + sKinv[7]*cxy.y + sKinv[8];
    float inr = 1.0f / sqrtf(dx*dx + dy*dy + dz*dz);
    dx *= inr; dy *= inr; dz *= inr;
    float wx = sRc[0]*dx + sRc[1]*dy + sRc[2]*dz;
    float wy = sRc[3]*dx + sRc[4]*dy + sRc[5]*dz;
    float wz = sRc[6]*dx + sRc[7]*dy + sRc[8]*dz;
    sSmall[t*3+0] = sOrig[0] + wx * dpt;
    sSmall[t*3+1] = sOrig[1] + wy * dpt;
    sSmall[t*3+2] = sOrig[2] + wz * dpt;
    float* cc = &sSmall[192 + t*9];
    cc[0]=C00; cc[1]=C01; cc[2]=C02; cc[3]=C01; cc[4]=C11; cc[5]=C12; cc[6]=C02; cc[7]=C12; cc[8]=C22;
    float* ss = &sSmall[768 + t*3]; ss[0]=sc0; ss[1]=sc1; ss[2]=sc2;
    float* rr = &sSmall[960 + t*4]; rr[0]=qr; rr[1]=qi; rr[2]=qj; rr[3]=qk;
    sSmall[1216 + t] = opac[gidx];
  } else {
    const int task = t - 64;        // 0..191
    const int gg = task & 63;
    const int ch = task >> 6;       // 0..2 (uniform per wave)
    const float* shin = &sIn[gg * RGS + 7 + ch * 25];
    float* shout = &sSh[gg * 75 + ch * 25];
    float in_[25];
#pragma unroll
    for (int j = 0; j < 25; ++j) in_[j] = shin[j];
    shout[0] = sD[0] * in_[0];
#pragma unroll
    for (int i = 0; i < 3; ++i) {
      float a = sD[1+i*3]*in_[1] + sD[1+i*3+1]*in_[2] + sD[1+i*3+2]*in_[3];
      shout[1 + i] = (float)(0.1 * 0.25) * a;
    }
#pragma unroll
    for (int i = 0; i < 5; ++i) {
      float a = 0.f;
#pragma unroll
      for (int j = 0; j < 5; ++j) a += sD[10 + i*5 + j] * in_[4 + j];
      shout[4 + i] = (float)(0.1 * 0.0625) * a;
    }
#pragma unroll
    for (int i = 0; i < 7; ++i) {
      float a = 0.f;
#pragma unroll
      for (int j = 0; j < 7; ++j) a += sD[35 + i*7 + j] * in_[9 + j];
      shout[9 + i] = (float)(0.1 * 0.015625) * a;
    }
#pragma unroll
    for (int i = 0; i < 9; ++i) {
      float a = 0.f;
#pragma unroll
      for (int j = 0; j < 9; ++j) a += sD[84 + i*9 + j] * in_[16 + j];
      shout[16 + i] = (float)(0.1 * 0.00390625) * a;
    }
  }
  __syncthreads();

  {
    float4* osh = (float4*)(out + OFF_SH + (size_t)g0 * 75);
    const float4* s4 = (const float4*)sSh;
    for (int idx = t; idx < 1200; idx += 256) osh[idx] = s4[idx];
    float* om  = out + OFF_MEANS + (size_t)g0 * 3;
    float* oc  = out + OFF_COV   + (size_t)g0 * 9;
    float* os  = out + OFF_SCL   + (size_t)g0 * 3;
    float* orr = out + OFF_ROT   + (size_t)g0 * 4;
    float* oo  = out + OFF_OP    + (size_t)g0;
    if (t < 192) { om[t] = sSmall[t]; os[t] = sSmall[768 + t]; }
    for (int idx = t; idx < 576; idx += 256) oc[idx] = sSmall[192 + idx];
    orr[t] = sSmall[960 + t];
    if (t < 64) oo[t] = sSmall[1216 + t];
  }
}

// ---------------- features transpose-broadcast ----------------
__global__ __launch_bounds__(256) void feat_kernel(
    const float* __restrict__ gf, float* __restrict__ out)
{
  __shared__ float tile[64 * 65];
  const int t = threadIdx.x;
  const int blk = blockIdx.x;      // 0..1023
  const int b = blk >> 8;
  const int hw0 = (blk & 255) << 6;
  const int tx = t & 63, ty = t >> 6;
  const float* src = gf + (size_t)b * 64 * 16384 + hw0;
#pragma unroll
  for (int i = 0; i < 16; ++i) {
    int c = i * 4 + ty;
    tile[c * 65 + tx] = src[(size_t)c * 16384 + tx];
  }
  __syncthreads();
  float* dst = out + OFF_FEAT + ((size_t)(b * 16384 + hw0)) * 3 * 64;
  for (int r = ty; r < 192; r += 4) {
    int hw = r / 3;
    dst[(size_t)r * 64 + tx] = tile[tx * 65 + hw];
  }
}

extern "C" void kernel_launch(void* const* d_in, const int* in_sizes, int n_in,
                              void* d_out, int out_size, void* d_ws, size_t ws_size,
                              hipStream_t stream)
{
  const float* extr   = (const float*)d_in[0];
  const float* intr   = (const float*)d_in[1];
  const float* coords = (const float*)d_in[2];
  const float* depths = (const float*)d_in[3];
  const float* opac   = (const float*)d_in[4];
  const float* rg     = (const float*)d_in[5];
  const float* gf     = (const float*)d_in[6];
  const int*   ih     = (const int*)d_in[7];
  const int*   iw     = (const int*)d_in[8];
  float* out = (float*)d_out;
  float* ws  = (float*)d_ws;

  hipLaunchKernelGGL(setup_kernel, dim3(20), dim3(256), 0, stream, extr, intr, ih, iw, ws);
  hipLaunchKernelGGL(gauss_kernel, dim3(N_TOT / 64), dim3(256), 0, stream,
                     extr, coords, depths, opac, rg, ws, out);
  hipLaunchKernelGGL(feat_kernel, dim3(1024), dim3(256), 0, stream, gf, out);
}